// Round 2
// baseline (3195.434 us; speedup 1.0000x reference)
//
#include <hip/hip_runtime.h>

#define N_F 512
#define N_C 1000
#define BM 128
#define BK 64
#define MARGIN 0.0625f        // bf16-logit error bound is ~0.01 worst case; 39 sigma

using short8  = __attribute__((ext_vector_type(8))) short;
using floatx4 = __attribute__((ext_vector_type(4))) float;

__device__ __forceinline__ unsigned short f2bf(float f) {
    unsigned u = __float_as_uint(f);
    unsigned r = u + 0x7FFFu + ((u >> 16) & 1u);   // RNE to bf16
    return (unsigned short)(r >> 16);
}
// monotone float->uint key so LDS atomicMax works for negative floats
__device__ __forceinline__ unsigned fkey(float f) {
    unsigned u = __float_as_uint(f);
    return (u & 0x80000000u) ? ~u : (u | 0x80000000u);
}
__device__ __forceinline__ float kinv(unsigned k) {
    unsigned u = (k & 0x80000000u) ? (k & 0x7FFFFFFFu) : ~k;
    return __uint_as_float(u);
}
// async 16B global->LDS. lds dest must be wave-uniform; HW adds lane*16.
__device__ __forceinline__ void gload_lds16(const void* g, void* l) {
    __builtin_amdgcn_global_load_lds((const __attribute__((address_space(1))) void*)g,
                                     (__attribute__((address_space(3))) void*)l, 16, 0, 0);
}

// ---------------- Phase 0a: stream x -> att_out(0.9x) + x_bf16 ---------------------
__global__ __launch_bounds__(256) void conv_x_kernel(
    const float* __restrict__ x, unsigned short* __restrict__ xbf,
    float* __restrict__ att, long n8)
{
    const long stride = (long)gridDim.x * 256;
    for (long i = (long)blockIdx.x * 256 + threadIdx.x; i < n8; i += stride) {
        const float4 a = ((const float4*)x)[2 * i];
        const float4 c = ((const float4*)x)[2 * i + 1];
        if (att) {
            float4 o0, o1;
            o0.x = 0.9f * a.x; o0.y = 0.9f * a.y; o0.z = 0.9f * a.z; o0.w = 0.9f * a.w;
            o1.x = 0.9f * c.x; o1.y = 0.9f * c.y; o1.z = 0.9f * c.z; o1.w = 0.9f * c.w;
            ((float4*)att)[2 * i]     = o0;
            ((float4*)att)[2 * i + 1] = o1;
        }
        short8 s;
        s[0] = (short)f2bf(a.x); s[1] = (short)f2bf(a.y);
        s[2] = (short)f2bf(a.z); s[3] = (short)f2bf(a.w);
        s[4] = (short)f2bf(c.x); s[5] = (short)f2bf(c.y);
        s[6] = (short)f2bf(c.z); s[7] = (short)f2bf(c.w);
        ((short8*)xbf)[i] = s;
    }
}

// ---------------- Phase 0b: W -> bf16 (zero-padded to 1024 rows) + zero worklist ---
__global__ __launch_bounds__(256) void conv_w_kernel(
    const float* __restrict__ W, unsigned short* __restrict__ wbf,
    int* __restrict__ wlCount)
{
    if (blockIdx.x == 0 && threadIdx.x == 0) wlCount[0] = 0;   // re-zeroed every launch
    const int r = blockIdx.x;      // 0..1023
    const int t = threadIdx.x;     // 256 threads * 2 elems = 512
    unsigned short v0 = 0, v1 = 0;
    if (r < N_C) {
        const float2 w2 = ((const float2*)(W + (size_t)r * N_F))[t];
        v0 = f2bf(w2.x); v1 = f2bf(w2.y);
    }
    wbf[(size_t)r * N_F + 2 * t]     = v0;
    wbf[(size_t)r * N_F + 2 * t + 1] = v1;
}

// ---------------- fallback: att_out = 0.9x (only when x_bf16 parked in att region) -
__global__ __launch_bounds__(256) void att_fix_kernel(
    const float* __restrict__ x, float* __restrict__ att, long n4)
{
    const long stride = (long)gridDim.x * 256;
    for (long i = (long)blockIdx.x * 256 + threadIdx.x; i < n4; i += stride) {
        const float4 a = ((const float4*)x)[i];
        float4 o;
        o.x = 0.9f * a.x; o.y = 0.9f * a.y; o.z = 0.9f * a.z; o.w = 0.9f * a.w;
        ((float4*)att)[i] = o;
    }
}

// ---------------- Phase 1: bf16 MFMA GEMM (global_load_lds staging) + argmax -------
// cnt==1 rows get their label written directly; ambiguous rows go to a worklist.
__global__ __launch_bounds__(256) void gemm_argmax_kernel(
    const unsigned short* __restrict__ xbf, const unsigned short* __restrict__ wbf,
    const float* __restrict__ b, int* __restrict__ candG,
    int* __restrict__ labels, int* __restrict__ wlCount, int* __restrict__ worklist)
{
    __shared__ unsigned short As[BM][BK];   // linear: required by global_load_lds
    __shared__ unsigned short Bs[BM][BK];
    __shared__ unsigned runmaxkey[BM];
    __shared__ int candCnt[BM];
    __shared__ int candLds[BM][7];

    const int tid  = threadIdx.x;
    const int rowBase = blockIdx.x * BM;
    const int lane = tid & 63;
    const int w    = tid >> 6;
    const int wm   = (w >> 1) * 64;   // wave row offset
    const int wn   = (w & 1) * 64;    // wave col offset
    const int quad = lane >> 4;
    const int l16  = lane & 15;

    if (tid < BM) { runmaxkey[tid] = 0u; candCnt[tid] = 0; }

    // staging geometry: per pass, wave w fills rows [p*32+w*8, +8), 8 chunks of 16B
    const int srow = w * 8 + (lane >> 3);          // 0..31
    const int scol = (lane & 7) * 8;               // bf16 elems
    const unsigned short* aG = xbf + (size_t)(rowBase + srow) * N_F + scol;
    const unsigned short* bG = wbf + (size_t)srow * N_F + scol;

    for (int ct = 0; ct < 8; ++ct) {
        floatx4 acc[4][4];
        #pragma unroll
        for (int mt = 0; mt < 4; ++mt)
            #pragma unroll
            for (int nt = 0; nt < 4; ++nt)
                acc[mt][nt] = (floatx4){0.f, 0.f, 0.f, 0.f};

        const int ctBase = ct * 128;
        const unsigned short* bGc = bG + (size_t)ctBase * N_F;

        for (int k0 = 0; k0 < N_F; k0 += BK) {
            __syncthreads();                       // LDS free of prior readers
            #pragma unroll
            for (int p = 0; p < 4; ++p) {
                gload_lds16(aG  + (size_t)p * 32 * N_F + k0, &As[p * 32 + w * 8][0]);
                gload_lds16(bGc + (size_t)p * 32 * N_F + k0, &Bs[p * 32 + w * 8][0]);
            }
            __syncthreads();                       // drains vmcnt(0): loads landed
            #pragma unroll
            for (int chunk = 0; chunk < 2; ++chunk) {
                const int koff = chunk * 32 + quad * 8;
                short8 af[4], bfr[4];
                #pragma unroll
                for (int mt = 0; mt < 4; ++mt)
                    af[mt] = *(const short8*)&As[wm + mt * 16 + l16][koff];
                #pragma unroll
                for (int nt = 0; nt < 4; ++nt)
                    bfr[nt] = *(const short8*)&Bs[wn + nt * 16 + l16][koff];
                #pragma unroll
                for (int mt = 0; mt < 4; ++mt)
                    #pragma unroll
                    for (int nt = 0; nt < 4; ++nt)
                        acc[mt][nt] = __builtin_amdgcn_mfma_f32_16x16x32_bf16(
                            af[mt], bfr[nt], acc[mt][nt], 0, 0, 0);
            }
        }

        // ---- epilogue for this class tile: running max, then candidate admission ----
        float bv[4]; bool valid[4]; int cls[4];
        #pragma unroll
        for (int nt = 0; nt < 4; ++nt) {
            const int c = ctBase + wn + nt * 16 + l16;
            cls[nt] = c; valid[nt] = (c < N_C);
            bv[nt]  = valid[nt] ? b[c] : 0.f;
        }
        #pragma unroll
        for (int mt = 0; mt < 4; ++mt) {
            #pragma unroll
            for (int i = 0; i < 4; ++i) {
                float m = -3e38f;
                #pragma unroll
                for (int nt = 0; nt < 4; ++nt) {
                    const float v = valid[nt] ? (acc[mt][nt][i] + bv[nt]) : -3e38f;
                    m = fmaxf(m, v);
                }
                m = fmaxf(m, __shfl_xor(m, 1, 64));
                m = fmaxf(m, __shfl_xor(m, 2, 64));
                m = fmaxf(m, __shfl_xor(m, 4, 64));
                m = fmaxf(m, __shfl_xor(m, 8, 64));
                if (l16 == 0) {
                    const int r = wm + mt * 16 + quad * 4 + i;
                    atomicMax(&runmaxkey[r], fkey(m));
                }
            }
        }
        __syncthreads();
        #pragma unroll
        for (int mt = 0; mt < 4; ++mt) {
            #pragma unroll
            for (int i = 0; i < 4; ++i) {
                const int r = wm + mt * 16 + quad * 4 + i;
                const float thresh = kinv(runmaxkey[r]) - MARGIN;
                #pragma unroll
                for (int nt = 0; nt < 4; ++nt) {
                    if (valid[nt]) {
                        const float v = acc[mt][nt][i] + bv[nt];
                        if (v > thresh) {
                            const int s = atomicAdd(&candCnt[r], 1);
                            if (s < 7) candLds[r][s] = cls[nt];
                        }
                    }
                }
            }
        }
    }

    __syncthreads();
    if (tid < BM) {
        const int R = rowBase + tid;
        const int cnt = candCnt[tid];
        if (cnt == 1) {                    // provably the fp32 argmax: resolve here
            labels[R] = candLds[tid][0];
        } else {                           // ambiguous: defer to fp64 recheck
            const int pos = atomicAdd(wlCount, 1);
            worklist[pos] = R;
            candG[(size_t)R * 8] = cnt;
            const int m = cnt < 7 ? cnt : 7;
            for (int s = 0; s < m; ++s) candG[(size_t)R * 8 + 1 + s] = candLds[tid][s];
        }
    }
}

// ---------------- Phase 1.5: fp64 recheck of AMBIGUOUS rows only (worklist) --------
__global__ __launch_bounds__(256) void label_kernel(
    const float* __restrict__ x, const float* __restrict__ W,
    const float* __restrict__ b, const int* __restrict__ candG,
    const int* __restrict__ wlCount, const int* __restrict__ worklist,
    int* __restrict__ labels)
{
    const int nAmb   = wlCount[0];
    const int waveId = blockIdx.x * 4 + (threadIdx.x >> 6);
    const int nWaves = gridDim.x * 4;
    const int lane   = threadIdx.x & 63;

    for (int idx = waveId; idx < nAmb; idx += nWaves) {
        const int row = worklist[idx];
        const int cnt = candG[(size_t)row * 8];
        const float* xr = x + (size_t)row * N_F;
        const float4 x0 = *(const float4*)&xr[lane * 8];
        const float4 x1 = *(const float4*)&xr[lane * 8 + 4];
        double best = -1e300; int bestc = 0x7fffffff;
        const bool all = (cnt > 7) || (cnt <= 0);   // overflow fallback: every class
        const int ncand = all ? N_C : cnt;
        for (int s = 0; s < ncand; ++s) {
            const int c = all ? s : candG[(size_t)row * 8 + 1 + s];
            const float* wc = W + (size_t)c * N_F + lane * 8;
            const float4 w0 = *(const float4*)&wc[0];
            const float4 w1 = *(const float4*)&wc[4];
            double p = (double)x0.x * w0.x + (double)x0.y * w0.y
                     + (double)x0.z * w0.z + (double)x0.w * w0.w
                     + (double)x1.x * w1.x + (double)x1.y * w1.y
                     + (double)x1.z * w1.z + (double)x1.w * w1.w;
            #pragma unroll
            for (int off = 1; off < 64; off <<= 1) p += __shfl_xor(p, off, 64);
            p += (double)b[c];
            if (p > best || (p == best && c < bestc)) { best = p; bestc = c; }
        }
        if (lane == 0) labels[row] = bestc;
    }
}

// ---------------- Phase 2: per-class gather (no atomics): counts, similarity, weight -
__global__ __launch_bounds__(256) void scatter_kernel(
    const float* __restrict__ x, const int* __restrict__ labels,
    const float* __restrict__ sim_init, const float* __restrict__ cnt_init,
    float* __restrict__ out_counts, float* __restrict__ out_sim,
    float* __restrict__ out_w, int N)
{
    const int c    = blockIdx.x;
    const int t    = threadIdx.x;
    const int w    = t >> 6;
    const int lane = t & 63;
    const int fbase = w * 128 + lane * 2;   // this wave's feature slice (float2)

    float acc0 = 0.f, acc1 = 0.f;
    int total = 0;
    for (int base = 0; base < N; base += 256) {
        const int4 l4 = *(const int4*)&labels[base + lane * 4];
        unsigned long long m0 = __ballot(l4.x == c);
        unsigned long long m1 = __ballot(l4.y == c);
        unsigned long long m2 = __ballot(l4.z == c);
        unsigned long long m3 = __ballot(l4.w == c);
        while (m0) { int bit = __ffsll(m0) - 1; m0 &= m0 - 1;
            const float2 v = *(const float2*)&x[(size_t)(base + bit * 4 + 0) * N_F + fbase];
            acc0 += v.x; acc1 += v.y; ++total; }
        while (m1) { int bit = __ffsll(m1) - 1; m1 &= m1 - 1;
            const float2 v = *(const float2*)&x[(size_t)(base + bit * 4 + 1) * N_F + fbase];
            acc0 += v.x; acc1 += v.y; ++total; }
        while (m2) { int bit = __ffsll(m2) - 1; m2 &= m2 - 1;
            const float2 v = *(const float2*)&x[(size_t)(base + bit * 4 + 2) * N_F + fbase];
            acc0 += v.x; acc1 += v.y; ++total; }
        while (m3) { int bit = __ffsll(m3) - 1; m3 &= m3 - 1;
            const float2 v = *(const float2*)&x[(size_t)(base + bit * 4 + 3) * N_F + fbase];
            acc0 += v.x; acc1 += v.y; ++total; }
    }
    const float countf = cnt_init[c] + (float)total;
    if (t == 0) out_counts[c] = countf;
    const float2 si = *(const float2*)&sim_init[(size_t)c * N_F + fbase];
    const float s0 = acc0 + si.x, s1 = acc1 + si.y;
    float2 so; so.x = s0; so.y = s1;
    *(float2*)&out_sim[(size_t)c * N_F + fbase] = so;
    float2 wo; wo.x = s0 / countf; wo.y = s1 / countf;
    *(float2*)&out_w[(size_t)c * N_F + fbase] = wo;
}

extern "C" void kernel_launch(void* const* d_in, const int* in_sizes, int n_in,
                              void* d_out, int out_size, void* d_ws, size_t ws_size,
                              hipStream_t stream) {
    const float* x        = (const float*)d_in[0];
    const float* W        = (const float*)d_in[1];
    const float* b        = (const float*)d_in[2];
    const float* sim_init = (const float*)d_in[3];
    const float* cnt_init = (const float*)d_in[4];
    const int N = in_sizes[0] / N_F;   // 131072

    float* out_att    = (float*)d_out;
    float* out_counts = out_att + (size_t)N * N_F;
    float* out_sim    = out_counts + N_C;
    float* out_w      = out_sim + (size_t)N_C * N_F;

    int* labels   = (int*)d_ws;              // N ints
    int* candG    = labels + N;              // N*8 ints
    int* wlCount  = candG + (size_t)N * 8;   // 4 ints (1 used)
    int* worklist = wlCount + 4;             // N ints

    const size_t baseWs    = (size_t)N * 4 + (size_t)N * 32 + 16 + (size_t)N * 4;
    const size_t xbfBytes  = (size_t)N * N_F * 2;        // 128 MB
    const size_t wbfBytes  = (size_t)1024 * N_F * 2;     // 1 MB (zero-padded rows)
    const bool bigws = ws_size >= baseWs + xbfBytes + wbfBytes;

    unsigned short *xbf, *wbf;
    if (bigws) {                        // Path A: bf16 copies live in workspace
        xbf = (unsigned short*)((char*)d_ws + baseWs);
        wbf = xbf + (size_t)N * N_F;
    } else {                            // Path B: park bf16 copies in att_out region,
        xbf = (unsigned short*)d_out;   //         rewrite att_out after the GEMM
        wbf = xbf + (size_t)N * N_F;
    }

    conv_x_kernel<<<2048, 256, 0, stream>>>(x, xbf, bigws ? out_att : nullptr,
                                            (long)N * N_F / 8);
    conv_w_kernel<<<1024, 256, 0, stream>>>(W, wbf, wlCount);
    gemm_argmax_kernel<<<N / BM, 256, 0, stream>>>(xbf, wbf, b, candG,
                                                   labels, wlCount, worklist);
    label_kernel<<<512, 256, 0, stream>>>(x, W, b, candG, wlCount, worklist, labels);
    scatter_kernel<<<N_C, 256, 0, stream>>>(x, labels, sim_init, cnt_init,
                                            out_counts, out_sim, out_w, N);
    if (!bigws)
        att_fix_kernel<<<2048, 256, 0, stream>>>(x, out_att, (long)N * N_F / 4);
}

// Round 3
// 1142.725 us; speedup vs baseline: 2.7963x; 2.7963x over previous
//
#include <hip/hip_runtime.h>

#define N_F 512
#define N_C 1000
#define BM 128
#define BK 64
#define MARGIN 0.0625f        // bf16-logit error bound is ~0.01 worst case; 39 sigma
#define NCAND 16              // raw admission slots per row (stale-threshold records)

using short8  = __attribute__((ext_vector_type(8))) short;
using floatx4 = __attribute__((ext_vector_type(4))) float;

__device__ __forceinline__ unsigned short f2bf(float f) {
    unsigned u = __float_as_uint(f);
    unsigned r = u + 0x7FFFu + ((u >> 16) & 1u);   // RNE to bf16
    return (unsigned short)(r >> 16);
}
// monotone float->uint key so LDS atomicMax works for negative floats
__device__ __forceinline__ unsigned fkey(float f) {
    unsigned u = __float_as_uint(f);
    return (u & 0x80000000u) ? ~u : (u | 0x80000000u);
}
__device__ __forceinline__ float kinv(unsigned k) {
    unsigned u = (k & 0x80000000u) ? (k & 0x7FFFFFFFu) : ~k;
    return __uint_as_float(u);
}
// async 16B global->LDS. lds dest must be wave-uniform; HW adds lane*16.
__device__ __forceinline__ void gload_lds16(const void* g, void* l) {
    __builtin_amdgcn_global_load_lds((const __attribute__((address_space(1))) void*)g,
                                     (__attribute__((address_space(3))) void*)l, 16, 0, 0);
}

// ---------------- Phase 0a: stream x -> att_out(0.9x) + x_bf16 ---------------------
__global__ __launch_bounds__(256) void conv_x_kernel(
    const float* __restrict__ x, unsigned short* __restrict__ xbf,
    float* __restrict__ att, long n8)
{
    const long stride = (long)gridDim.x * 256;
    for (long i = (long)blockIdx.x * 256 + threadIdx.x; i < n8; i += stride) {
        const float4 a = ((const float4*)x)[2 * i];
        const float4 c = ((const float4*)x)[2 * i + 1];
        if (att) {
            float4 o0, o1;
            o0.x = 0.9f * a.x; o0.y = 0.9f * a.y; o0.z = 0.9f * a.z; o0.w = 0.9f * a.w;
            o1.x = 0.9f * c.x; o1.y = 0.9f * c.y; o1.z = 0.9f * c.z; o1.w = 0.9f * c.w;
            ((float4*)att)[2 * i]     = o0;
            ((float4*)att)[2 * i + 1] = o1;
        }
        short8 s;
        s[0] = (short)f2bf(a.x); s[1] = (short)f2bf(a.y);
        s[2] = (short)f2bf(a.z); s[3] = (short)f2bf(a.w);
        s[4] = (short)f2bf(c.x); s[5] = (short)f2bf(c.y);
        s[6] = (short)f2bf(c.z); s[7] = (short)f2bf(c.w);
        ((short8*)xbf)[i] = s;
    }
}

// ---------------- Phase 0b: W -> bf16 (zero-padded to 1024 rows) + zero worklist ---
__global__ __launch_bounds__(256) void conv_w_kernel(
    const float* __restrict__ W, unsigned short* __restrict__ wbf,
    int* __restrict__ wlCount)
{
    if (blockIdx.x == 0 && threadIdx.x == 0) wlCount[0] = 0;   // re-zeroed every launch
    const int r = blockIdx.x;      // 0..1023
    const int t = threadIdx.x;     // 256 threads * 2 elems = 512
    unsigned short v0 = 0, v1 = 0;
    if (r < N_C) {
        const float2 w2 = ((const float2*)(W + (size_t)r * N_F))[t];
        v0 = f2bf(w2.x); v1 = f2bf(w2.y);
    }
    wbf[(size_t)r * N_F + 2 * t]     = v0;
    wbf[(size_t)r * N_F + 2 * t + 1] = v1;
}

// ---------------- fallback: att_out = 0.9x (only when x_bf16 parked in att region) -
__global__ __launch_bounds__(256) void att_fix_kernel(
    const float* __restrict__ x, float* __restrict__ att, long n4)
{
    const long stride = (long)gridDim.x * 256;
    for (long i = (long)blockIdx.x * 256 + threadIdx.x; i < n4; i += stride) {
        const float4 a = ((const float4*)x)[i];
        float4 o;
        o.x = 0.9f * a.x; o.y = 0.9f * a.y; o.z = 0.9f * a.z; o.w = 0.9f * a.w;
        ((float4*)att)[i] = o;
    }
}

// ---------------- Phase 1: bf16 MFMA GEMM (global_load_lds staging) + argmax -------
// Admission vs running max (as before), but candidates keep their VALUE; a final
// pass refilters against the GLOBAL row max, so stale record-tile admissions die.
__global__ __launch_bounds__(256) void gemm_argmax_kernel(
    const unsigned short* __restrict__ xbf, const unsigned short* __restrict__ wbf,
    const float* __restrict__ b, int* __restrict__ candG,
    int* __restrict__ labels, int* __restrict__ wlCount, int* __restrict__ worklist)
{
    __shared__ unsigned short As[BM][BK];   // linear: required by global_load_lds
    __shared__ unsigned short Bs[BM][BK];
    __shared__ unsigned runmaxkey[BM];
    __shared__ int candCnt[BM];
    __shared__ float candVal[BM][NCAND];
    __shared__ int   candCls[BM][NCAND];

    const int tid  = threadIdx.x;
    const int rowBase = blockIdx.x * BM;
    const int lane = tid & 63;
    const int w    = tid >> 6;
    const int wm   = (w >> 1) * 64;   // wave row offset
    const int wn   = (w & 1) * 64;    // wave col offset
    const int quad = lane >> 4;
    const int l16  = lane & 15;

    if (tid < BM) { runmaxkey[tid] = 0u; candCnt[tid] = 0; }

    // staging geometry: per pass, wave w fills rows [p*32+w*8, +8), 8 chunks of 16B
    const int srow = w * 8 + (lane >> 3);          // 0..31
    const int scol = (lane & 7) * 8;               // bf16 elems
    const unsigned short* aG = xbf + (size_t)(rowBase + srow) * N_F + scol;
    const unsigned short* bG = wbf + (size_t)srow * N_F + scol;

    for (int ct = 0; ct < 8; ++ct) {
        floatx4 acc[4][4];
        #pragma unroll
        for (int mt = 0; mt < 4; ++mt)
            #pragma unroll
            for (int nt = 0; nt < 4; ++nt)
                acc[mt][nt] = (floatx4){0.f, 0.f, 0.f, 0.f};

        const int ctBase = ct * 128;
        const unsigned short* bGc = bG + (size_t)ctBase * N_F;

        for (int k0 = 0; k0 < N_F; k0 += BK) {
            __syncthreads();                       // LDS free of prior readers
            #pragma unroll
            for (int p = 0; p < 4; ++p) {
                gload_lds16(aG  + (size_t)p * 32 * N_F + k0, &As[p * 32 + w * 8][0]);
                gload_lds16(bGc + (size_t)p * 32 * N_F + k0, &Bs[p * 32 + w * 8][0]);
            }
            __syncthreads();                       // drains vmcnt(0): loads landed
            #pragma unroll
            for (int chunk = 0; chunk < 2; ++chunk) {
                const int koff = chunk * 32 + quad * 8;
                short8 af[4], bfr[4];
                #pragma unroll
                for (int mt = 0; mt < 4; ++mt)
                    af[mt] = *(const short8*)&As[wm + mt * 16 + l16][koff];
                #pragma unroll
                for (int nt = 0; nt < 4; ++nt)
                    bfr[nt] = *(const short8*)&Bs[wn + nt * 16 + l16][koff];
                #pragma unroll
                for (int mt = 0; mt < 4; ++mt)
                    #pragma unroll
                    for (int nt = 0; nt < 4; ++nt)
                        acc[mt][nt] = __builtin_amdgcn_mfma_f32_16x16x32_bf16(
                            af[mt], bfr[nt], acc[mt][nt], 0, 0, 0);
            }
        }

        // ---- epilogue for this class tile: running max, then candidate admission ----
        float bv[4]; bool valid[4]; int cls[4];
        #pragma unroll
        for (int nt = 0; nt < 4; ++nt) {
            const int c = ctBase + wn + nt * 16 + l16;
            cls[nt] = c; valid[nt] = (c < N_C);
            bv[nt]  = valid[nt] ? b[c] : 0.f;
        }
        #pragma unroll
        for (int mt = 0; mt < 4; ++mt) {
            #pragma unroll
            for (int i = 0; i < 4; ++i) {
                float m = -3e38f;
                #pragma unroll
                for (int nt = 0; nt < 4; ++nt) {
                    const float v = valid[nt] ? (acc[mt][nt][i] + bv[nt]) : -3e38f;
                    m = fmaxf(m, v);
                }
                m = fmaxf(m, __shfl_xor(m, 1, 64));
                m = fmaxf(m, __shfl_xor(m, 2, 64));
                m = fmaxf(m, __shfl_xor(m, 4, 64));
                m = fmaxf(m, __shfl_xor(m, 8, 64));
                if (l16 == 0) {
                    const int r = wm + mt * 16 + quad * 4 + i;
                    atomicMax(&runmaxkey[r], fkey(m));
                }
            }
        }
        __syncthreads();
        #pragma unroll
        for (int mt = 0; mt < 4; ++mt) {
            #pragma unroll
            for (int i = 0; i < 4; ++i) {
                const int r = wm + mt * 16 + quad * 4 + i;
                const float thresh = kinv(runmaxkey[r]) - MARGIN;
                #pragma unroll
                for (int nt = 0; nt < 4; ++nt) {
                    if (valid[nt]) {
                        const float v = acc[mt][nt][i] + bv[nt];
                        if (v > thresh) {
                            const int s = atomicAdd(&candCnt[r], 1);
                            if (s < NCAND) { candVal[r][s] = v; candCls[r][s] = cls[nt]; }
                        }
                    }
                }
            }
        }
    }

    // ---- final: refilter stored candidates against the GLOBAL row max ------------
    __syncthreads();
    if (tid < BM) {
        const int R = rowBase + tid;
        const int raw = candCnt[tid];
        if (raw > NCAND) {
            // a true candidate may have been dropped: full recheck (P ~ 0)
            const int pos = atomicAdd(wlCount, 1);
            worklist[pos] = R;
            candG[(size_t)R * 8] = -1;
        } else {
            const float thresh = kinv(runmaxkey[tid]) - MARGIN;
            int cnt = 0; int keep[7];
            for (int s = 0; s < raw; ++s) {
                if (candVal[tid][s] > thresh) {
                    if (cnt < 7) keep[cnt] = candCls[tid][s];
                    ++cnt;
                }
            }
            if (cnt == 1) {                 // provably the fp32 argmax: resolve here
                labels[R] = keep[0];
            } else {                        // genuinely ambiguous: defer to fp64
                const int pos = atomicAdd(wlCount, 1);
                worklist[pos] = R;
                candG[(size_t)R * 8] = (cnt > 7) ? -1 : cnt;
                const int m = cnt < 7 ? cnt : 7;
                for (int s = 0; s < m; ++s) candG[(size_t)R * 8 + 1 + s] = keep[s];
            }
        }
    }
}

// ---------------- Phase 1.5: fp64 recheck of AMBIGUOUS rows only (worklist) --------
__global__ __launch_bounds__(256) void label_kernel(
    const float* __restrict__ x, const float* __restrict__ W,
    const float* __restrict__ b, const int* __restrict__ candG,
    const int* __restrict__ wlCount, const int* __restrict__ worklist,
    int* __restrict__ labels)
{
    const int nAmb   = wlCount[0];
    const int waveId = blockIdx.x * 4 + (threadIdx.x >> 6);
    const int nWaves = gridDim.x * 4;
    const int lane   = threadIdx.x & 63;

    for (int idx = waveId; idx < nAmb; idx += nWaves) {
        const int row = worklist[idx];
        const int cnt = candG[(size_t)row * 8];
        const float* xr = x + (size_t)row * N_F;
        const float4 x0 = *(const float4*)&xr[lane * 8];
        const float4 x1 = *(const float4*)&xr[lane * 8 + 4];
        double best = -1e300; int bestc = 0x7fffffff;
        const bool all = (cnt < 0);             // overflow fallback: every class
        const int ncand = all ? N_C : cnt;
        for (int s = 0; s < ncand; ++s) {
            const int c = all ? s : candG[(size_t)row * 8 + 1 + s];
            const float* wc = W + (size_t)c * N_F + lane * 8;
            const float4 w0 = *(const float4*)&wc[0];
            const float4 w1 = *(const float4*)&wc[4];
            double p = (double)x0.x * w0.x + (double)x0.y * w0.y
                     + (double)x0.z * w0.z + (double)x0.w * w0.w
                     + (double)x1.x * w1.x + (double)x1.y * w1.y
                     + (double)x1.z * w1.z + (double)x1.w * w1.w;
            #pragma unroll
            for (int off = 1; off < 64; off <<= 1) p += __shfl_xor(p, off, 64);
            p += (double)b[c];
            if (p > best || (p == best && c < bestc)) { best = p; bestc = c; }
        }
        if (lane == 0) labels[row] = bestc;
    }
}

// ---------------- Phase 2: per-class gather (no atomics): counts, similarity, weight -
__global__ __launch_bounds__(256) void scatter_kernel(
    const float* __restrict__ x, const int* __restrict__ labels,
    const float* __restrict__ sim_init, const float* __restrict__ cnt_init,
    float* __restrict__ out_counts, float* __restrict__ out_sim,
    float* __restrict__ out_w, int N)
{
    const int c    = blockIdx.x;
    const int t    = threadIdx.x;
    const int w    = t >> 6;
    const int lane = t & 63;
    const int fbase = w * 128 + lane * 2;   // this wave's feature slice (float2)

    float acc0 = 0.f, acc1 = 0.f;
    int total = 0;
    for (int base = 0; base < N; base += 256) {
        const int4 l4 = *(const int4*)&labels[base + lane * 4];
        unsigned long long m0 = __ballot(l4.x == c);
        unsigned long long m1 = __ballot(l4.y == c);
        unsigned long long m2 = __ballot(l4.z == c);
        unsigned long long m3 = __ballot(l4.w == c);
        while (m0) { int bit = __ffsll(m0) - 1; m0 &= m0 - 1;
            const float2 v = *(const float2*)&x[(size_t)(base + bit * 4 + 0) * N_F + fbase];
            acc0 += v.x; acc1 += v.y; ++total; }
        while (m1) { int bit = __ffsll(m1) - 1; m1 &= m1 - 1;
            const float2 v = *(const float2*)&x[(size_t)(base + bit * 4 + 1) * N_F + fbase];
            acc0 += v.x; acc1 += v.y; ++total; }
        while (m2) { int bit = __ffsll(m2) - 1; m2 &= m2 - 1;
            const float2 v = *(const float2*)&x[(size_t)(base + bit * 4 + 2) * N_F + fbase];
            acc0 += v.x; acc1 += v.y; ++total; }
        while (m3) { int bit = __ffsll(m3) - 1; m3 &= m3 - 1;
            const float2 v = *(const float2*)&x[(size_t)(base + bit * 4 + 3) * N_F + fbase];
            acc0 += v.x; acc1 += v.y; ++total; }
    }
    const float countf = cnt_init[c] + (float)total;
    if (t == 0) out_counts[c] = countf;
    const float2 si = *(const float2*)&sim_init[(size_t)c * N_F + fbase];
    const float s0 = acc0 + si.x, s1 = acc1 + si.y;
    float2 so; so.x = s0; so.y = s1;
    *(float2*)&out_sim[(size_t)c * N_F + fbase] = so;
    float2 wo; wo.x = s0 / countf; wo.y = s1 / countf;
    *(float2*)&out_w[(size_t)c * N_F + fbase] = wo;
}

extern "C" void kernel_launch(void* const* d_in, const int* in_sizes, int n_in,
                              void* d_out, int out_size, void* d_ws, size_t ws_size,
                              hipStream_t stream) {
    const float* x        = (const float*)d_in[0];
    const float* W        = (const float*)d_in[1];
    const float* b        = (const float*)d_in[2];
    const float* sim_init = (const float*)d_in[3];
    const float* cnt_init = (const float*)d_in[4];
    const int N = in_sizes[0] / N_F;   // 131072

    float* out_att    = (float*)d_out;
    float* out_counts = out_att + (size_t)N * N_F;
    float* out_sim    = out_counts + N_C;
    float* out_w      = out_sim + (size_t)N_C * N_F;

    int* labels   = (int*)d_ws;              // N ints
    int* candG    = labels + N;              // N*8 ints
    int* wlCount  = candG + (size_t)N * 8;   // 4 ints (1 used)
    int* worklist = wlCount + 4;             // N ints

    const size_t baseWs    = (size_t)N * 4 + (size_t)N * 32 + 16 + (size_t)N * 4;
    const size_t xbfBytes  = (size_t)N * N_F * 2;        // 128 MB
    const size_t wbfBytes  = (size_t)1024 * N_F * 2;     // 1 MB (zero-padded rows)
    const bool bigws = ws_size >= baseWs + xbfBytes + wbfBytes;

    unsigned short *xbf, *wbf;
    if (bigws) {                        // Path A: bf16 copies live in workspace
        xbf = (unsigned short*)((char*)d_ws + baseWs);
        wbf = xbf + (size_t)N * N_F;
    } else {                            // Path B: park bf16 copies in att_out region,
        xbf = (unsigned short*)d_out;   //         rewrite att_out after the GEMM
        wbf = xbf + (size_t)N * N_F;
    }

    conv_x_kernel<<<2048, 256, 0, stream>>>(x, xbf, bigws ? out_att : nullptr,
                                            (long)N * N_F / 8);
    conv_w_kernel<<<1024, 256, 0, stream>>>(W, wbf, wlCount);
    gemm_argmax_kernel<<<N / BM, 256, 0, stream>>>(xbf, wbf, b, candG,
                                                   labels, wlCount, worklist);
    label_kernel<<<4096, 256, 0, stream>>>(x, W, b, candG, wlCount, worklist, labels);
    scatter_kernel<<<N_C, 256, 0, stream>>>(x, labels, sim_init, cnt_init,
                                            out_counts, out_sim, out_w, N);
    if (!bigws)
        att_fix_kernel<<<2048, 256, 0, stream>>>(x, out_att, (long)N * N_F / 4);
}

// Round 4
// 812.086 us; speedup vs baseline: 3.9348x; 1.4071x over previous
//
#include <hip/hip_runtime.h>

#define N_F 512
#define N_C 1000
#define BM 128
#define BN 256                // classes per pass (4 passes over 1024 padded classes)
#define BK 64
#define MARGIN 0.0625f        // bf16-logit error bound is ~0.01 worst case; 39 sigma
#define NCAND 16              // raw admission slots per row (stale-threshold records)

using short8  = __attribute__((ext_vector_type(8))) short;
using floatx4 = __attribute__((ext_vector_type(4))) float;

__device__ __forceinline__ unsigned short f2bf(float f) {
    unsigned u = __float_as_uint(f);
    unsigned r = u + 0x7FFFu + ((u >> 16) & 1u);   // RNE to bf16
    return (unsigned short)(r >> 16);
}
// monotone float->uint key so LDS atomicMax works for negative floats
__device__ __forceinline__ unsigned fkey(float f) {
    unsigned u = __float_as_uint(f);
    return (u & 0x80000000u) ? ~u : (u | 0x80000000u);
}
__device__ __forceinline__ float kinv(unsigned k) {
    unsigned u = (k & 0x80000000u) ? (k & 0x7FFFFFFFu) : ~k;
    return __uint_as_float(u);
}
// async 16B global->LDS. lds dest must be wave-uniform; HW adds lane*16.
__device__ __forceinline__ void gload_lds16(const void* g, void* l) {
    __builtin_amdgcn_global_load_lds((const __attribute__((address_space(1))) void*)g,
                                     (__attribute__((address_space(3))) void*)l, 16, 0, 0);
}

// ---------------- Phase 0a: stream x -> att_out(0.9x) + x_bf16 ---------------------
__global__ __launch_bounds__(256) void conv_x_kernel(
    const float* __restrict__ x, unsigned short* __restrict__ xbf,
    float* __restrict__ att, long n8)
{
    const long stride = (long)gridDim.x * 256;
    for (long i = (long)blockIdx.x * 256 + threadIdx.x; i < n8; i += stride) {
        const float4 a = ((const float4*)x)[2 * i];
        const float4 c = ((const float4*)x)[2 * i + 1];
        if (att) {
            float4 o0, o1;
            o0.x = 0.9f * a.x; o0.y = 0.9f * a.y; o0.z = 0.9f * a.z; o0.w = 0.9f * a.w;
            o1.x = 0.9f * c.x; o1.y = 0.9f * c.y; o1.z = 0.9f * c.z; o1.w = 0.9f * c.w;
            ((float4*)att)[2 * i]     = o0;
            ((float4*)att)[2 * i + 1] = o1;
        }
        short8 s;
        s[0] = (short)f2bf(a.x); s[1] = (short)f2bf(a.y);
        s[2] = (short)f2bf(a.z); s[3] = (short)f2bf(a.w);
        s[4] = (short)f2bf(c.x); s[5] = (short)f2bf(c.y);
        s[6] = (short)f2bf(c.z); s[7] = (short)f2bf(c.w);
        ((short8*)xbf)[i] = s;
    }
}

// ---------------- Phase 0b: W -> bf16 (zero-padded to 1024 rows) + zero worklist ---
__global__ __launch_bounds__(256) void conv_w_kernel(
    const float* __restrict__ W, unsigned short* __restrict__ wbf,
    int* __restrict__ wlCount)
{
    if (blockIdx.x == 0 && threadIdx.x == 0) wlCount[0] = 0;   // re-zeroed every launch
    const int r = blockIdx.x;      // 0..1023
    const int t = threadIdx.x;     // 256 threads * 2 elems = 512
    unsigned short v0 = 0, v1 = 0;
    if (r < N_C) {
        const float2 w2 = ((const float2*)(W + (size_t)r * N_F))[t];
        v0 = f2bf(w2.x); v1 = f2bf(w2.y);
    }
    wbf[(size_t)r * N_F + 2 * t]     = v0;
    wbf[(size_t)r * N_F + 2 * t + 1] = v1;
}

// ---------------- fallback: att_out = 0.9x (only when x_bf16 parked in att region) -
__global__ __launch_bounds__(256) void att_fix_kernel(
    const float* __restrict__ x, float* __restrict__ att, long n4)
{
    const long stride = (long)gridDim.x * 256;
    for (long i = (long)blockIdx.x * 256 + threadIdx.x; i < n4; i += stride) {
        const float4 a = ((const float4*)x)[i];
        float4 o;
        o.x = 0.9f * a.x; o.y = 0.9f * a.y; o.z = 0.9f * a.z; o.w = 0.9f * a.w;
        ((float4*)att)[i] = o;
    }
}

// ---------------- Phase 1: bf16 MFMA GEMM (global_load_lds staging) + argmax -------
// BN=256 class pass (halves x re-staging). LDS bank conflicts killed by XOR-swizzle:
// staging loads logical 16B-chunk (lane&7)^(lane>>3), so LDS[r][phys p] holds
// logical chunk p^(r&7); reads XOR the same term back (rule: both-sides-or-neither).
__global__ __launch_bounds__(256, 2) void gemm_argmax_kernel(
    const unsigned short* __restrict__ xbf, const unsigned short* __restrict__ wbf,
    const float* __restrict__ b, int* __restrict__ candG,
    int* __restrict__ labels, int* __restrict__ wlCount, int* __restrict__ worklist)
{
    __shared__ unsigned short As[BM][BK];   // 16 KB, linear (global_load_lds dest)
    __shared__ unsigned short Bs[BN][BK];   // 32 KB, linear
    __shared__ unsigned runmaxkey[BM];
    __shared__ int candCnt[BM];
    __shared__ float candVal[BM][NCAND];
    __shared__ int   candCls[BM][NCAND];

    const int tid  = threadIdx.x;
    const int rowBase = blockIdx.x * BM;
    const int lane = tid & 63;
    const int w    = tid >> 6;
    const int wm   = (w >> 1) * 64;    // wave row offset (2 row-waves)
    const int wn   = (w & 1) * 128;    // wave col offset (2 col-waves over 256)
    const int quad = lane >> 4;
    const int l16  = lane & 15;

    if (tid < BM) { runmaxkey[tid] = 0u; candCnt[tid] = 0; }

    // staging: wave w fills rows [p*32+w*8, +8); lane -> row w*8+(lane>>3),
    // SWIZZLED logical chunk (lane&7)^(lane>>3) of the 8x16B row slice.
    const int srow   = w * 8 + (lane >> 3);
    const int schunk = (lane & 7) ^ (lane >> 3);
    const unsigned short* aG = xbf + (size_t)(rowBase + srow) * N_F + schunk * 8;
    const unsigned short* bG = wbf + (size_t)srow * N_F + schunk * 8;

    for (int ctg = 0; ctg < 4; ++ctg) {
        floatx4 acc[4][8];
        #pragma unroll
        for (int mt = 0; mt < 4; ++mt)
            #pragma unroll
            for (int nt = 0; nt < 8; ++nt)
                acc[mt][nt] = (floatx4){0.f, 0.f, 0.f, 0.f};

        const int ctBase = ctg * BN;
        const unsigned short* bGc = bG + (size_t)ctBase * N_F;

        for (int k0 = 0; k0 < N_F; k0 += BK) {
            __syncthreads();                       // LDS free of prior readers
            #pragma unroll
            for (int p = 0; p < 4; ++p)
                gload_lds16(aG  + (size_t)p * 32 * N_F + k0, &As[p * 32 + w * 8][0]);
            #pragma unroll
            for (int p = 0; p < 8; ++p)
                gload_lds16(bGc + (size_t)p * 32 * N_F + k0, &Bs[p * 32 + w * 8][0]);
            __syncthreads();                       // drains vmcnt(0): loads landed
            #pragma unroll
            for (int chunk = 0; chunk < 2; ++chunk) {
                const int pcol = ((chunk * 4 + quad) ^ (l16 & 7)) * 8;  // de-swizzle
                short8 af[4], bfr[8];
                #pragma unroll
                for (int mt = 0; mt < 4; ++mt)
                    af[mt] = *(const short8*)&As[wm + mt * 16 + l16][pcol];
                #pragma unroll
                for (int nt = 0; nt < 8; ++nt)
                    bfr[nt] = *(const short8*)&Bs[wn + nt * 16 + l16][pcol];
                #pragma unroll
                for (int mt = 0; mt < 4; ++mt)
                    #pragma unroll
                    for (int nt = 0; nt < 8; ++nt)
                        acc[mt][nt] = __builtin_amdgcn_mfma_f32_16x16x32_bf16(
                            af[mt], bfr[nt], acc[mt][nt], 0, 0, 0);
            }
        }

        // ---- epilogue for this class pass: running max, then candidate admission ----
        float bv[8]; bool valid[8]; int cls[8];
        #pragma unroll
        for (int nt = 0; nt < 8; ++nt) {
            const int c = ctBase + wn + nt * 16 + l16;
            cls[nt] = c; valid[nt] = (c < N_C);
            bv[nt]  = valid[nt] ? b[c] : 0.f;
        }
        #pragma unroll
        for (int mt = 0; mt < 4; ++mt) {
            #pragma unroll
            for (int i = 0; i < 4; ++i) {
                float m = -3e38f;
                #pragma unroll
                for (int nt = 0; nt < 8; ++nt) {
                    const float v = valid[nt] ? (acc[mt][nt][i] + bv[nt]) : -3e38f;
                    m = fmaxf(m, v);
                }
                m = fmaxf(m, __shfl_xor(m, 1, 64));
                m = fmaxf(m, __shfl_xor(m, 2, 64));
                m = fmaxf(m, __shfl_xor(m, 4, 64));
                m = fmaxf(m, __shfl_xor(m, 8, 64));
                if (l16 == 0) {
                    const int r = wm + mt * 16 + quad * 4 + i;
                    atomicMax(&runmaxkey[r], fkey(m));
                }
            }
        }
        __syncthreads();
        #pragma unroll
        for (int mt = 0; mt < 4; ++mt) {
            #pragma unroll
            for (int i = 0; i < 4; ++i) {
                const int r = wm + mt * 16 + quad * 4 + i;
                const float thresh = kinv(runmaxkey[r]) - MARGIN;
                #pragma unroll
                for (int nt = 0; nt < 8; ++nt) {
                    if (valid[nt]) {
                        const float v = acc[mt][nt][i] + bv[nt];
                        if (v > thresh) {
                            const int s = atomicAdd(&candCnt[r], 1);
                            if (s < NCAND) { candVal[r][s] = v; candCls[r][s] = cls[nt]; }
                        }
                    }
                }
            }
        }
    }

    // ---- final: refilter stored candidates against the GLOBAL row max ------------
    __syncthreads();
    if (tid < BM) {
        const int R = rowBase + tid;
        const int raw = candCnt[tid];
        if (raw > NCAND) {
            // a true candidate may have been dropped: full recheck (P ~ 0)
            const int pos = atomicAdd(wlCount, 1);
            worklist[pos] = R;
            candG[(size_t)R * 8] = -1;
        } else {
            const float thresh = kinv(runmaxkey[tid]) - MARGIN;
            int cnt = 0; int keep[7];
            for (int s = 0; s < raw; ++s) {
                if (candVal[tid][s] > thresh) {
                    if (cnt < 7) keep[cnt] = candCls[tid][s];
                    ++cnt;
                }
            }
            if (cnt == 1) {                 // provably the fp32 argmax: resolve here
                labels[R] = keep[0];
            } else {                        // genuinely ambiguous: defer to fp64
                const int pos = atomicAdd(wlCount, 1);
                worklist[pos] = R;
                candG[(size_t)R * 8] = (cnt > 7) ? -1 : cnt;
                const int m = cnt < 7 ? cnt : 7;
                for (int s = 0; s < m; ++s) candG[(size_t)R * 8 + 1 + s] = keep[s];
            }
        }
    }
}

// ---------------- Phase 1.5: fp64 recheck of AMBIGUOUS rows only (worklist) --------
__global__ __launch_bounds__(256) void label_kernel(
    const float* __restrict__ x, const float* __restrict__ W,
    const float* __restrict__ b, const int* __restrict__ candG,
    const int* __restrict__ wlCount, const int* __restrict__ worklist,
    int* __restrict__ labels)
{
    const int nAmb   = wlCount[0];
    const int waveId = blockIdx.x * 4 + (threadIdx.x >> 6);
    const int nWaves = gridDim.x * 4;
    const int lane   = threadIdx.x & 63;

    for (int idx = waveId; idx < nAmb; idx += nWaves) {
        const int row = worklist[idx];
        const int cnt = candG[(size_t)row * 8];
        const float* xr = x + (size_t)row * N_F;
        const float4 x0 = *(const float4*)&xr[lane * 8];
        const float4 x1 = *(const float4*)&xr[lane * 8 + 4];
        double best = -1e300; int bestc = 0x7fffffff;
        const bool all = (cnt < 0);             // overflow fallback: every class
        const int ncand = all ? N_C : cnt;
        for (int s = 0; s < ncand; ++s) {
            const int c = all ? s : candG[(size_t)row * 8 + 1 + s];
            const float* wc = W + (size_t)c * N_F + lane * 8;
            const float4 w0 = *(const float4*)&wc[0];
            const float4 w1 = *(const float4*)&wc[4];
            double p = (double)x0.x * w0.x + (double)x0.y * w0.y
                     + (double)x0.z * w0.z + (double)x0.w * w0.w
                     + (double)x1.x * w1.x + (double)x1.y * w1.y
                     + (double)x1.z * w1.z + (double)x1.w * w1.w;
            #pragma unroll
            for (int off = 1; off < 64; off <<= 1) p += __shfl_xor(p, off, 64);
            p += (double)b[c];
            if (p > best || (p == best && c < bestc)) { best = p; bestc = c; }
        }
        if (lane == 0) labels[row] = bestc;
    }
}

// ---------------- Phase 2: per-class gather: each wave scans a quarter of N --------
__global__ __launch_bounds__(256) void scatter_kernel(
    const float* __restrict__ x, const int* __restrict__ labels,
    const float* __restrict__ sim_init, const float* __restrict__ cnt_init,
    float* __restrict__ out_counts, float* __restrict__ out_sim,
    float* __restrict__ out_w, int N)
{
    __shared__ float psum[4][N_F];
    __shared__ int ptot[4];
    const int c    = blockIdx.x;
    const int t    = threadIdx.x;
    const int w    = t >> 6;
    const int lane = t & 63;

    // each wave owns rows [w*N/4, (w+1)*N/4) and the FULL feature row (8 f/lane)
    float a0=0.f,a1=0.f,a2=0.f,a3=0.f,a4=0.f,a5=0.f,a6=0.f,a7=0.f;
    int total = 0;
    const int quarter = N >> 2;
    const int qbeg = w * quarter;
    for (int base = 0; base < quarter; base += 256) {
        const int4 l4 = *(const int4*)&labels[qbeg + base + lane * 4];
        unsigned long long m0 = __ballot(l4.x == c);
        unsigned long long m1 = __ballot(l4.y == c);
        unsigned long long m2 = __ballot(l4.z == c);
        unsigned long long m3 = __ballot(l4.w == c);
        #define POP(mm, sub) \
        while (mm) { int bit = __ffsll(mm) - 1; mm &= mm - 1; \
            const float* xr = &x[(size_t)(qbeg + base + bit * 4 + sub) * N_F + lane * 8]; \
            const float4 v0 = *(const float4*)&xr[0]; \
            const float4 v1 = *(const float4*)&xr[4]; \
            a0 += v0.x; a1 += v0.y; a2 += v0.z; a3 += v0.w; \
            a4 += v1.x; a5 += v1.y; a6 += v1.z; a7 += v1.w; ++total; }
        POP(m0, 0) POP(m1, 1) POP(m2, 2) POP(m3, 3)
        #undef POP
    }
    float* ps = &psum[w][lane * 8];
    ps[0]=a0; ps[1]=a1; ps[2]=a2; ps[3]=a3; ps[4]=a4; ps[5]=a5; ps[6]=a6; ps[7]=a7;
    if (lane == 0) ptot[w] = total;
    __syncthreads();

    const int f = t * 2;                     // 256 threads x 2 features = 512
    const float s0p = psum[0][f]   + psum[1][f]   + psum[2][f]   + psum[3][f];
    const float s1p = psum[0][f+1] + psum[1][f+1] + psum[2][f+1] + psum[3][f+1];
    const float countf = cnt_init[c] + (float)(ptot[0] + ptot[1] + ptot[2] + ptot[3]);
    if (t == 0) out_counts[c] = countf;
    const float2 si = *(const float2*)&sim_init[(size_t)c * N_F + f];
    const float s0 = s0p + si.x, s1 = s1p + si.y;
    float2 so; so.x = s0; so.y = s1;
    *(float2*)&out_sim[(size_t)c * N_F + f] = so;
    float2 wo; wo.x = s0 / countf; wo.y = s1 / countf;
    *(float2*)&out_w[(size_t)c * N_F + f] = wo;
}

extern "C" void kernel_launch(void* const* d_in, const int* in_sizes, int n_in,
                              void* d_out, int out_size, void* d_ws, size_t ws_size,
                              hipStream_t stream) {
    const float* x        = (const float*)d_in[0];
    const float* W        = (const float*)d_in[1];
    const float* b        = (const float*)d_in[2];
    const float* sim_init = (const float*)d_in[3];
    const float* cnt_init = (const float*)d_in[4];
    const int N = in_sizes[0] / N_F;   // 131072

    float* out_att    = (float*)d_out;
    float* out_counts = out_att + (size_t)N * N_F;
    float* out_sim    = out_counts + N_C;
    float* out_w      = out_sim + (size_t)N_C * N_F;

    int* labels   = (int*)d_ws;              // N ints
    int* candG    = labels + N;              // N*8 ints
    int* wlCount  = candG + (size_t)N * 8;   // 4 ints (1 used)
    int* worklist = wlCount + 4;             // N ints

    const size_t baseWs    = (size_t)N * 4 + (size_t)N * 32 + 16 + (size_t)N * 4;
    const size_t xbfBytes  = (size_t)N * N_F * 2;        // 128 MB
    const size_t wbfBytes  = (size_t)1024 * N_F * 2;     // 1 MB (zero-padded rows)
    const bool bigws = ws_size >= baseWs + xbfBytes + wbfBytes;

    unsigned short *xbf, *wbf;
    if (bigws) {                        // Path A: bf16 copies live in workspace
        xbf = (unsigned short*)((char*)d_ws + baseWs);
        wbf = xbf + (size_t)N * N_F;
    } else {                            // Path B: park bf16 copies in att_out region,
        xbf = (unsigned short*)d_out;   //         rewrite att_out after the GEMM
        wbf = xbf + (size_t)N * N_F;
    }

    conv_x_kernel<<<2048, 256, 0, stream>>>(x, xbf, bigws ? out_att : nullptr,
                                            (long)N * N_F / 8);
    conv_w_kernel<<<1024, 256, 0, stream>>>(W, wbf, wlCount);
    gemm_argmax_kernel<<<N / BM, 256, 0, stream>>>(xbf, wbf, b, candG,
                                                   labels, wlCount, worklist);
    label_kernel<<<4096, 256, 0, stream>>>(x, W, b, candG, wlCount, worklist, labels);
    scatter_kernel<<<N_C, 256, 0, stream>>>(x, labels, sim_init, cnt_init,
                                            out_counts, out_sim, out_w, N);
    if (!bigws)
        att_fix_kernel<<<2048, 256, 0, stream>>>(x, out_att, (long)N * N_F / 4);
}